// Round 16
// baseline (381.995 us; speedup 1.0000x reference)
//
#include <hip/hip_runtime.h>
#include <hip/hip_bf16.h>
#include <float.h>

#define NS 32768
#define KER 256
#define TOUT 32513
#define NATOM 256
#define NSTEP 16
#define BATCH 8
#define NBLK 255
#define SW4(i) ((i) + (((i) >> 5) << 2))

typedef __attribute__((ext_vector_type(8))) _Float16 half8;
typedef __attribute__((ext_vector_type(16))) float f32x16;
typedef __attribute__((ext_vector_type(4))) unsigned int uint4v;
typedef unsigned long long u64;

__device__ __forceinline__ void cmax(float& ba, float& bs, float& bi,
                                     float oa, float os, float oi) {
    if (oa > ba || (oa == ba && oi < bi)) { ba = oa; bs = os; bi = oi; }
}

// u64 key <-> (sig, idx): key = abs_bits<<32 | (0x7FFFFF-idx)<<1 | signbit.
// Integer order == cmax total order (abs desc, idx asc). Keys are distinct
// (idx unique) -> max is reduction-order independent.
__device__ __forceinline__ u64 packkey(float sig, int idx) {
    return ((u64)__float_as_uint(fabsf(sig)) << 32)
         | ((u64)((0x7FFFFFu - (unsigned int)idx) << 1))
         | (u64)(__float_as_uint(sig) >> 31);
}
__device__ __forceinline__ void unpackkey(u64 k, float& sig, int& idx) {
    const float av = __uint_as_float((unsigned int)(k >> 32));
    const unsigned int lo = (unsigned int)k;
    idx = 0x7FFFFF - (int)((lo >> 1) & 0x7FFFFFu);
    sig = (lo & 1u) ? -av : av;
}

__device__ __forceinline__ void fma8(float acc[8], float4 dA, float4 dB,
                                     float4 w0, float4 w1, float4 w2, float4 w3) {
    float w[16] = {w0.x,w0.y,w0.z,w0.w, w1.x,w1.y,w1.z,w1.w,
                   w2.x,w2.y,w2.z,w2.w, w3.x,w3.y,w3.z,w3.w};
    float dv[8] = {dA.x,dA.y,dA.z,dA.w, dB.x,dB.y,dB.z,dB.w};
#pragma unroll
    for (int i = 0; i < 8; ++i)
#pragma unroll
        for (int j = 0; j < 8; ++j)
            acc[j] = fmaf(dv[i], w[i + j], acc[j]);
}

__device__ __forceinline__ unsigned int f16hi(float v) {
    return (unsigned int)__builtin_bit_cast(unsigned short, (_Float16)v);
}
__device__ __forceinline__ unsigned int f16lo(float v) {
    const _Float16 h = (_Float16)v;
    return (unsigned int)__builtin_bit_cast(unsigned short, (_Float16)(v - (float)h));
}

// d split + l2k zeroing (memset folded in; one fewer dispatch).
__global__ __launch_bounds__(256) void k_prep(const float* __restrict__ d,
                                              uint4* __restrict__ dhF,
                                              uint4* __restrict__ dlF,
                                              u64* __restrict__ l2k) {
    const int j = blockIdx.x * 256 + threadIdx.x;
    if (j < NATOM * 32) {
        const int kg = j >> 8, atom = j & 255;
        const float* dp = d + atom * 256 + (kg << 3);
        uint4 hw, lw;
        hw.x = f16hi(dp[0]) | (f16hi(dp[1]) << 16);
        hw.y = f16hi(dp[2]) | (f16hi(dp[3]) << 16);
        hw.z = f16hi(dp[4]) | (f16hi(dp[5]) << 16);
        hw.w = f16hi(dp[6]) | (f16hi(dp[7]) << 16);
        lw.x = f16lo(dp[0]) | (f16lo(dp[1]) << 16);
        lw.y = f16lo(dp[2]) | (f16lo(dp[3]) << 16);
        lw.z = f16lo(dp[4]) | (f16lo(dp[5]) << 16);
        lw.w = f16lo(dp[6]) | (f16lo(dp[7]) << 16);
        dhF[(kg << 8) + atom] = hw;
        dlF[(kg << 8) + atom] = lw;
    } else if (j < NATOM * 32 + 2 * BATCH * NATOM) {
        l2k[j - NATOM * 32] = 0ull;   // key 0 = identity for max
    }
}

// 32x32x16_f16 MFMA correlation, 2m x 2n tile, diagonal-B register FIFO.
// grid (128 c, 4 mg of 64 atoms, 8 b), block 256.
// r16: pre-reduced epilogue — 2-level shfl_xor before LDS store, keyL
// 33.9KB -> 9.2KB (stride-9 bank spread), 4x fewer tail reads. Same key
// sets, max is order-independent -> bm/l2 bit-identical to r15.
__global__ __launch_bounds__(256) void k_init(const float* __restrict__ x,
                                              const uint4* __restrict__ dhF,
                                              const uint4* __restrict__ dlF,
                                              float2* __restrict__ bm,
                                              u64* __restrict__ l2k) {
    const int c = blockIdx.x, mg = blockIdx.y, b = blockIdx.z;
    const int tid = threadIdx.x;
    const int w = tid >> 6, l = tid & 63;
    const int n = l & 31, h = l >> 5;
    __shared__ float xs[520];
    __shared__ uint4 xw[512];          // packed quads {hi01,hi23,lo01,lo23}
    __shared__ u64 keyL[1152];         // 4 waves x 32 amt x (8 slots, pad 9)
    const int t0 = c << 8;
    const float* xp = x + (size_t)b * NS;
    for (int i4 = tid; i4 < 130; i4 += 256) {
        const int i = i4 << 2, g = t0 + i;
        float4 v;
        if (g + 3 < NS) v = *(const float4*)(xp + g);
        else {
            v.x = (g     < NS) ? xp[g]     : 0.f;
            v.y = (g + 1 < NS) ? xp[g + 1] : 0.f;
            v.z = (g + 2 < NS) ? xp[g + 2] : 0.f;
            v.w = (g + 3 < NS) ? xp[g + 3] : 0.f;
        }
        *(float4*)(xs + i) = v;
    }
    __syncthreads();
    for (int i = tid; i < 512; i += 256) {
        const float v0 = xs[i], v1 = xs[i + 1], v2 = xs[i + 2], v3 = xs[i + 3];
        uint4 q;
        q.x = f16hi(v0) | (f16hi(v1) << 16);
        q.y = f16hi(v2) | (f16hi(v3) << 16);
        q.z = f16lo(v0) | (f16lo(v1) << 16);
        q.w = f16lo(v2) | (f16lo(v3) << 16);
        xw[i] = q;
    }
    __syncthreads();

    f32x16 acc00, acc01, acc10, acc11;
#pragma unroll
    for (int j = 0; j < 16; ++j) { acc00[j] = 0.f; acc01[j] = 0.f;
                                   acc10[j] = 0.f; acc11[j] = 0.f; }

    const int abase = (mg << 6) + n;
    const int sbb = (w << 6) + n + (h << 3);

    half8 fbh[4], fbl[4];
    {
        const uint4 q0 = xw[sbb], q1 = xw[sbb + 4];
        const uint4v hv = {q0.x, q0.y, q1.x, q1.y};
        const uint4v lv = {q0.z, q0.w, q1.z, q1.w};
        fbh[0] = __builtin_bit_cast(half8, hv);
        fbl[0] = __builtin_bit_cast(half8, lv);
    }
    {
        const uint4 q0 = xw[sbb + 16], q1 = xw[sbb + 20];
        const uint4v hv = {q0.x, q0.y, q1.x, q1.y};
        const uint4v lv = {q0.z, q0.w, q1.z, q1.w};
        fbh[1] = __builtin_bit_cast(half8, hv);
        fbl[1] = __builtin_bit_cast(half8, lv);
    }

#pragma unroll 4
    for (int kk = 0; kk < 16; ++kk) {
        const int kg = (kk << 1) + h;
        const half8 ah0 = __builtin_bit_cast(half8, dhF[(kg << 8) + abase]);
        const half8 al0 = __builtin_bit_cast(half8, dlF[(kg << 8) + abase]);
        const half8 ah1 = __builtin_bit_cast(half8, dhF[(kg << 8) + abase + 32]);
        const half8 al1 = __builtin_bit_cast(half8, dlF[(kg << 8) + abase + 32]);
        {
            const int sN = sbb + ((kk + 2) << 4);
            const uint4 q0 = xw[sN], q1 = xw[sN + 4];
            const uint4v hv = {q0.x, q0.y, q1.x, q1.y};
            const uint4v lv = {q0.z, q0.w, q1.z, q1.w};
            fbh[(kk + 2) & 3] = __builtin_bit_cast(half8, hv);
            fbl[(kk + 2) & 3] = __builtin_bit_cast(half8, lv);
        }
        const half8 b0h = fbh[kk & 3],       b0l = fbl[kk & 3];
        const half8 b1h = fbh[(kk + 2) & 3], b1l = fbl[(kk + 2) & 3];
        acc00 = __builtin_amdgcn_mfma_f32_32x32x16_f16(ah0, b0l, acc00, 0, 0, 0);
        acc00 = __builtin_amdgcn_mfma_f32_32x32x16_f16(al0, b0h, acc00, 0, 0, 0);
        acc00 = __builtin_amdgcn_mfma_f32_32x32x16_f16(ah0, b0h, acc00, 0, 0, 0);
        acc10 = __builtin_amdgcn_mfma_f32_32x32x16_f16(ah1, b0l, acc10, 0, 0, 0);
        acc10 = __builtin_amdgcn_mfma_f32_32x32x16_f16(al1, b0h, acc10, 0, 0, 0);
        acc10 = __builtin_amdgcn_mfma_f32_32x32x16_f16(ah1, b0h, acc10, 0, 0, 0);
        acc01 = __builtin_amdgcn_mfma_f32_32x32x16_f16(ah0, b1l, acc01, 0, 0, 0);
        acc01 = __builtin_amdgcn_mfma_f32_32x32x16_f16(al0, b1h, acc01, 0, 0, 0);
        acc01 = __builtin_amdgcn_mfma_f32_32x32x16_f16(ah0, b1h, acc01, 0, 0, 0);
        acc11 = __builtin_amdgcn_mfma_f32_32x32x16_f16(ah1, b1l, acc11, 0, 0, 0);
        acc11 = __builtin_amdgcn_mfma_f32_32x32x16_f16(al1, b1h, acc11, 0, 0, 0);
        acc11 = __builtin_amdgcn_mfma_f32_32x32x16_f16(ah1, b1h, acc11, 0, 0, 0);
    }

    // Epilogue. C layout: col=lane&31 (t), row=(r&3)+8*(r>>2)+4*h (atom in 32).
    // Per r: key = max(k0,k1); 2-level xor pre-reduce; n%4==0 lanes store.
    // Tail: 64 instances (amt, p2) x 4 sub; 4 reads + 2 shuffle levels each.
    const int tb = t0 + (w << 6) + n;
#pragma unroll
    for (int mt = 0; mt < 2; ++mt) {
#pragma unroll
        for (int r = 0; r < 16; ++r) {
            const int amt = (r & 3) + ((r >> 2) << 3) + (h << 2);
            const int idx0 = ((mg << 6) + (mt << 5) + amt) * TOUT + tb;
            const float v0 = (mt == 0) ? acc00[r] : acc10[r];
            const float v1 = (mt == 0) ? acc01[r] : acc11[r];
            const unsigned int c0 = (0x7FFFFFu - (unsigned int)idx0);
            u64 k0 = 0ull, k1 = 0ull;
            if (tb < TOUT)
                k0 = ((u64)__float_as_uint(fabsf(v0)) << 32)
                   | ((u64)(c0 << 1))
                   | (u64)(__float_as_uint(v0) >> 31);
            if (tb + 32 < TOUT)
                k1 = ((u64)__float_as_uint(fabsf(v1)) << 32)
                   | ((u64)((c0 - 32u) << 1))
                   | (u64)(__float_as_uint(v1) >> 31);
            u64 k = (k1 > k0) ? k1 : k0;
#pragma unroll
            for (int m = 1; m <= 2; m <<= 1) {
                const u64 ok = __shfl_xor(k, m, 32);
                if (ok > k) k = ok;
            }
            if ((n & 3) == 0) keyL[w * 288 + amt * 9 + (n >> 2)] = k;
        }
        __syncthreads();
        {
            const int inst = tid >> 2, sub = tid & 3;   // inst = amt*2 + p2
            const int p2 = inst & 1, amt = inst >> 1;
            u64 k = 0ull;
#pragma unroll
            for (int j = 0; j < 4; ++j) {
                const int e = sub * 4 + j;              // 16 entries: 2 waves x 8
                const int wv = (p2 << 1) + (e >> 3);
                const u64 ke = keyL[wv * 288 + amt * 9 + (e & 7)];
                if (ke > k) k = ke;
            }
#pragma unroll
            for (int m = 1; m <= 2; m <<= 1) {
                const u64 ok = __shfl_xor(k, m, 4);
                if (ok > k) k = ok;
            }
            const int blk = (c << 1) + p2;
            const int atom = (mg << 6) + (mt << 5) + amt;
            if (sub == 0 && blk < NBLK) {
                float bsg; int idx;
                unpackkey(k, bsg, idx);
                bm[(size_t)((b << 8) + atom) * NBLK + blk] =
                    make_float2(bsg, (float)idx);
            }
            const u64 op = __shfl_xor(k, 4, 8);          // partner p2's max
            if ((tid & 7) == 0) {
                const u64 km = (op > k) ? op : k;
                if (km) atomicMax(&l2k[(b << 8) + atom], km);
            }
        }
        __syncthreads();
    }
}

// One MP step (unchanged from r15, bit-proven).
__global__ __launch_bounds__(512) void k_step(const float* __restrict__ d,
                                              const float* __restrict__ resid_src,
                                              float* __restrict__ resid_dst,
                                              float2* __restrict__ bm,
                                              u64* __restrict__ l2,
                                              int* __restrict__ pos_a,
                                              int* __restrict__ atom_a,
                                              float* __restrict__ amp_a,
                                              int step) {
    const int og = blockIdx.x, b = blockIdx.y;
    const int tid = threadIdx.x;
    const int wave = tid >> 6, lane = tid & 63;
    __shared__ float dt[2048];
    __shared__ float rsu[1024];
    __shared__ u64 sred[8];
    __shared__ float4 upd[8][5];
    __shared__ int sh_pos, sh_atom, sh_prev;
    __shared__ float sh_amp;

    ((float4*)dt)[tid] = ((const float4*)(d + og * 2048))[tid];
    if (tid == 0 && step >= 2) sh_prev = pos_a[(step - 1) * BATCH + b];
    u64* l2r = l2 + (step & 1) * (BATCH * NATOM);
    u64* l2w = l2 + ((step + 1) & 1) * (BATCH * NATOM);

    {
        u64 k = 0ull;
        if (tid < 256) k = l2r[(b << 8) + tid];
#pragma unroll
        for (int m = 1; m <= 32; m <<= 1) {
            const u64 ok = __shfl_xor(k, m);
            if (ok > k) k = ok;
        }
        if (lane == 0) sred[wave] = k;
    }
    __syncthreads();
    if (tid == 0) {
        u64 k = sred[0];
#pragma unroll
        for (int i = 1; i < 8; ++i) if (sred[i] > k) k = sred[i];
        float sig; int idx;
        unpackkey(k, sig, idx);
        const int atom = idx / TOUT;
        const int pos = idx - atom * TOUT;
        sh_pos = pos; sh_atom = atom; sh_amp = sig;
        if (og == 0) {
            pos_a[step * BATCH + b] = pos;
            atom_a[step * BATCH + b] = atom;
            amp_a[step * BATCH + b] = sig;
        }
    }
    __syncthreads();
    const int p = sh_pos, atom_s = sh_atom;
    const float amp = sh_amp;

    if (step < 2) {
        for (int i = tid; i < 1024; i += 512) {
            const int g = (og << 10) + i;
            float v = resid_src[(size_t)b * NS + g];
            const int off = g - p;
            if (off >= 0 && off < KER)
                v = __fsub_rn(v, __fmul_rn(amp, d[atom_s * KER + off]));
            resid_dst[(size_t)b * NS + g] = v;
        }
    } else if (og == 0) {
        if (tid < 256) {
            const int g = p + tid;
            resid_dst[(size_t)b * NS + g] =
                __fsub_rn(resid_src[(size_t)b * NS + g],
                          __fmul_rn(amp, d[atom_s * KER + tid]));
        } else {
            const int g = sh_prev + (tid - 256);
            if (g < p || g > p + 255)
                resid_dst[(size_t)b * NS + g] = resid_src[(size_t)b * NS + g];
        }
    }

    int tlo = p - 255; if (tlo < 0) tlo = 0;
    int thi = p + 255; if (thi > TOUT - 1) thi = TOUT - 1;
    const int bs0 = tlo >> 7, be0 = thi >> 7;
    const int rbase = bs0 << 7;
    const int nblks = be0 - bs0 + 1;
    const int rlen = (nblks << 7) + 255;
    for (int i = tid; i < rlen; i += 512) {
        const int g = rbase + i;
        float v = (g < NS) ? resid_src[(size_t)b * NS + g] : 0.f;
        const int off = g - p;
        if (g < NS && off >= 0 && off < KER)
            v = __fsub_rn(v, __fmul_rn(amp, d[atom_s * KER + off]));
        rsu[SW4(i)] = v;
    }
    __syncthreads();

    const int lg = lane >> 4, l16 = lane & 15;
    const float* dp = dt + (wave << 8) + (lg << 6);
    const int atomg = (og << 3) + wave;
    for (int bb = 0; bb < nblks; ++bb) {
        const int blk = bs0 + bb;
        const int t0r = (bb << 7) + (l16 << 3) + (lg << 6);
        float acc[8];
#pragma unroll
        for (int j = 0; j < 8; ++j) acc[j] = 0.f;
        float4 A0 = *(const float4*)(rsu + SW4(t0r));
        float4 A1 = *(const float4*)(rsu + SW4(t0r + 4));
        float4 B0 = *(const float4*)(rsu + SW4(t0r + 8));
        float4 B1 = *(const float4*)(rsu + SW4(t0r + 12));
#pragma unroll
        for (int kk = 0; kk < 64; kk += 16) {
            const float4 d0 = *(const float4*)(dp + kk);
            const float4 d1 = *(const float4*)(dp + kk + 4);
            const float4 N0 = *(const float4*)(rsu + SW4(t0r + kk + 16));
            const float4 N1 = *(const float4*)(rsu + SW4(t0r + kk + 20));
            fma8(acc, d0, d1, A0, A1, B0, B1);
            const float4 d2 = *(const float4*)(dp + kk + 8);
            const float4 d3 = *(const float4*)(dp + kk + 12);
            const float4 M0 = *(const float4*)(rsu + SW4(t0r + kk + 24));
            const float4 M1 = *(const float4*)(rsu + SW4(t0r + kk + 28));
            fma8(acc, d2, d3, B0, B1, N0, N1);
            A0 = N0; A1 = N1; B0 = M0; B1 = M1;
        }
#pragma unroll
        for (int j = 0; j < 8; ++j) {
            acc[j] += __shfl_xor(acc[j], 16);
            acc[j] += __shfl_xor(acc[j], 32);
        }
        float ba = -1.f, bsg = 0.f, bi = 3.0e7f;
        const int tbp = rbase + (bb << 7) + (l16 << 3);
#pragma unroll
        for (int j = 0; j < 8; ++j) {
            const int t = tbp + j;
            const float av = fabsf(acc[j]);
            if (t < TOUT && av > ba) { ba = av; bsg = acc[j]; bi = (float)(atomg * TOUT + t); }
        }
#pragma unroll
        for (int m = 32; m >= 1; m >>= 1) {
            const float oa = __shfl_xor(ba, m);
            const float os = __shfl_xor(bsg, m);
            const float oi = __shfl_xor(bi, m);
            cmax(ba, bsg, bi, oa, os, oi);
        }
        if (lane == 0) {
            bm[(size_t)(b * NATOM + atomg) * NBLK + blk] = make_float2(bsg, bi);
            upd[wave][bb] = make_float4(ba, bsg, bi, 0.f);
        }
    }
    __syncthreads();

    {
        const u64 ko = l2r[(b << 8) + atomg];
        float eox; int eidx;
        unpackkey(ko, eox, eidx);
        const int oblk = (eidx - atomg * TOUT) >> 7;
        if (oblk >= bs0 && oblk <= be0) {
            float ba = -1.f, bsg = 0.f, bi = 3.0e7f;
            const float2* row = bm + (size_t)(b * NATOM + atomg) * NBLK;
            for (int i = lane; i < NBLK; i += 64) {
                if (i >= bs0 && i <= be0) {
                    const float4 e2 = upd[wave][i - bs0];
                    cmax(ba, bsg, bi, e2.x, e2.y, e2.z);
                } else {
                    const float2 e2 = row[i];
                    cmax(ba, bsg, bi, fabsf(e2.x), e2.x, e2.y);
                }
            }
#pragma unroll
            for (int m = 32; m >= 1; m >>= 1) {
                const float oa = __shfl_xor(ba, m);
                const float os = __shfl_xor(bsg, m);
                const float oi = __shfl_xor(bi, m);
                cmax(ba, bsg, bi, oa, os, oi);
            }
            if (lane == 0) l2w[(b << 8) + atomg] = packkey(bsg, (int)bi);
        } else if (lane == 0) {
            u64 k = ko;
            for (int bb = 0; bb < nblks; ++bb) {
                const float4 e2 = upd[wave][bb];
                const u64 ku = packkey(e2.y, (int)e2.z);
                if (ku > k) k = ku;
            }
            l2w[(b << 8) + atomg] = k;
        }
    }
}

// Head; blocks with s==15 compute the final select inline from l2 parity buf.
__global__ __launch_bounds__(128) void k_head(const int* __restrict__ pos_a,
                                              const int* __restrict__ atom_a,
                                              const float* __restrict__ amp_a,
                                              const u64* __restrict__ l2,
                                              const float* __restrict__ wpa,
                                              const float* __restrict__ bpa,
                                              const float* __restrict__ wat,
                                              const float* __restrict__ bat,
                                              const float* __restrict__ wr,
                                              const float* __restrict__ br,
                                              float* __restrict__ out) {
    const int s = blockIdx.x, b = blockIdx.y;
    const int o = threadIdx.x;
    __shared__ u64 hred[2];
    __shared__ int sh_pos, sh_atom;
    __shared__ float sh_amp;
    int pos, atom; float amp;
    if (s == NSTEP - 1) {
        const u64* l2r = l2 + ((NSTEP - 1) & 1) * (BATCH * NATOM);
        u64 k = l2r[(b << 8) + o];
        const u64 k2 = l2r[(b << 8) + 128 + o];
        if (k2 > k) k = k2;
#pragma unroll
        for (int m = 1; m <= 32; m <<= 1) {
            const u64 ok = __shfl_xor(k, m);
            if (ok > k) k = ok;
        }
        if ((o & 63) == 0) hred[o >> 6] = k;
        __syncthreads();
        if (o == 0) {
            u64 r = hred[0];
            if (hred[1] > r) r = hred[1];
            float sig; int idx;
            unpackkey(r, sig, idx);
            sh_atom = idx / TOUT;
            sh_pos = idx - sh_atom * TOUT;
            sh_amp = sig;
        }
        __syncthreads();
        pos = sh_pos; atom = sh_atom; amp = sh_amp;
    } else {
        pos  = pos_a[s * BATCH + b];
        atom = atom_a[s * BATCH + b];
        amp  = amp_a[s * BATCH + b];
    }
    const float posn = (float)pos / 32513.0f;
    float sum = br[o];
    for (int c = 0; c < 128; ++c) {
        const float pa = wpa[c * 2] * posn + wpa[c * 2 + 1] * amp + bpa[c];
        const float at = wat[c * 256 + atom] + bat[c];
        sum += wr[o * 256 + c] * pa + wr[o * 256 + 128 + c] * at;
    }
    out[(b * 128 + o) * NSTEP + s] = sum;
}

extern "C" void kernel_launch(void* const* d_in, const int* in_sizes, int n_in,
                              void* d_out, int out_size, void* d_ws, size_t ws_size,
                              hipStream_t stream) {
    const float* x   = (const float*)d_in[0];
    const float* d   = (const float*)d_in[1];
    const float* wpa = (const float*)d_in[2];
    const float* bpa = (const float*)d_in[3];
    const float* wat = (const float*)d_in[4];
    const float* bat = (const float*)d_in[5];
    const float* wr  = (const float*)d_in[6];
    const float* br  = (const float*)d_in[7];
    float* out = (float*)d_out;

    char* ws = (char*)d_ws;
    float2* bm    = (float2*)ws;                                    // 4,177,920
    u64*    l2k   = (u64*)(ws + 4177920);                           // 32,768
    int*    pos_a  = (int*)(ws + 4210688);                          // 512
    int*    atom_a = (int*)(ws + 4211200);                          // 512
    float*  amp_a  = (float*)(ws + 4211712);                        // 512
    uint4*  dhF    = (uint4*)(ws + 4212224);                        // 131,072
    uint4*  dlF    = (uint4*)(ws + 4343296);                        // 131,072
    float*  resid0 = (float*)(ws + 4474368);                        // 1,048,576
    float*  resid1 = (float*)(ws + 5522944);                        // 1,048,576

    const int prep_n = NATOM * 32 + 2 * BATCH * NATOM;              // 12288
    k_prep<<<(prep_n + 255) / 256, 256, 0, stream>>>(d, dhF, dlF, l2k);
    k_init<<<dim3(128, 4, 8), 256, 0, stream>>>(x, dhF, dlF, bm, l2k);
    // Step 0 reads x directly (r_0 = x); steps 0/1 fully populate dst buffers,
    // steps >=2 write only the two changed 256-sample windows.
    for (int st = 0; st < NSTEP - 1; ++st) {
        const float* rs = (st == 0) ? x : ((st & 1) ? resid1 : resid0);
        float* rd = (st & 1) ? resid0 : resid1;
        k_step<<<dim3(32, 8), 512, 0, stream>>>(d, rs, rd, bm, l2k,
                                                pos_a, atom_a, amp_a, st);
    }
    k_head<<<dim3(16, 8), 128, 0, stream>>>(pos_a, atom_a, amp_a, l2k,
                                            wpa, bpa, wat, bat, wr, br, out);
}

// Round 18
// 369.249 us; speedup vs baseline: 1.0345x; 1.0345x over previous
//
#include <hip/hip_runtime.h>
#include <hip/hip_bf16.h>
#include <float.h>

#define NS 32768
#define KER 256
#define TOUT 32513
#define NATOM 256
#define NSTEP 16
#define BATCH 8
#define NBLK 255
#define SW4(i) ((i) + (((i) >> 5) << 2))
#define KW 1060   // u64 stride per wave in keyL (bank-spread)

typedef __attribute__((ext_vector_type(8))) _Float16 half8;
typedef __attribute__((ext_vector_type(16))) float f32x16;
typedef __attribute__((ext_vector_type(4))) unsigned int uint4v;
typedef unsigned long long u64;

__device__ __forceinline__ void cmax(float& ba, float& bs, float& bi,
                                     float oa, float os, float oi) {
    if (oa > ba || (oa == ba && oi < bi)) { ba = oa; bs = os; bi = oi; }
}

// u64 key <-> (sig, idx): key = abs_bits<<32 | (0x7FFFFF-idx)<<1 | signbit.
// Integer order == cmax total order (abs desc, idx asc); keys distinct.
__device__ __forceinline__ u64 packkey(float sig, int idx) {
    return ((u64)__float_as_uint(fabsf(sig)) << 32)
         | ((u64)((0x7FFFFFu - (unsigned int)idx) << 1))
         | (u64)(__float_as_uint(sig) >> 31);
}
__device__ __forceinline__ void unpackkey(u64 k, float& sig, int& idx) {
    const float av = __uint_as_float((unsigned int)(k >> 32));
    const unsigned int lo = (unsigned int)k;
    idx = 0x7FFFFF - (int)((lo >> 1) & 0x7FFFFFu);
    sig = (lo & 1u) ? -av : av;
}

__device__ __forceinline__ void fma8(float acc[8], float4 dA, float4 dB,
                                     float4 w0, float4 w1, float4 w2, float4 w3) {
    float w[16] = {w0.x,w0.y,w0.z,w0.w, w1.x,w1.y,w1.z,w1.w,
                   w2.x,w2.y,w2.z,w2.w, w3.x,w3.y,w3.z,w3.w};
    float dv[8] = {dA.x,dA.y,dA.z,dA.w, dB.x,dB.y,dB.z,dB.w};
#pragma unroll
    for (int i = 0; i < 8; ++i)
#pragma unroll
        for (int j = 0; j < 8; ++j)
            acc[j] = fmaf(dv[i], w[i + j], acc[j]);
}

__device__ __forceinline__ unsigned int f16hi(float v) {
    return (unsigned int)__builtin_bit_cast(unsigned short, (_Float16)v);
}
__device__ __forceinline__ unsigned int f16lo(float v) {
    const _Float16 h = (_Float16)v;
    return (unsigned int)__builtin_bit_cast(unsigned short, (_Float16)(v - (float)h));
}

// d split + l2k zeroing (memset folded in; one fewer dispatch).
__global__ __launch_bounds__(256) void k_prep(const float* __restrict__ d,
                                              uint4* __restrict__ dhF,
                                              uint4* __restrict__ dlF,
                                              u64* __restrict__ l2k) {
    const int j = blockIdx.x * 256 + threadIdx.x;
    if (j < NATOM * 32) {
        const int kg = j >> 8, atom = j & 255;
        const float* dp = d + atom * 256 + (kg << 3);
        uint4 hw, lw;
        hw.x = f16hi(dp[0]) | (f16hi(dp[1]) << 16);
        hw.y = f16hi(dp[2]) | (f16hi(dp[3]) << 16);
        hw.z = f16hi(dp[4]) | (f16hi(dp[5]) << 16);
        hw.w = f16hi(dp[6]) | (f16hi(dp[7]) << 16);
        lw.x = f16lo(dp[0]) | (f16lo(dp[1]) << 16);
        lw.y = f16lo(dp[2]) | (f16lo(dp[3]) << 16);
        lw.z = f16lo(dp[4]) | (f16lo(dp[5]) << 16);
        lw.w = f16lo(dp[6]) | (f16lo(dp[7]) << 16);
        dhF[(kg << 8) + atom] = hw;
        dlF[(kg << 8) + atom] = lw;
    } else if (j < NATOM * 32 + 2 * BATCH * NATOM) {
        l2k[j - NATOM * 32] = 0ull;   // key 0 = identity for max
    }
}

// 32x32x16_f16 MFMA correlation, 2m x 2n tile, diagonal-B register FIFO.
// r15 version verbatim (best measured: 105 us, MfmaUtil 46%).
__global__ __launch_bounds__(256) void k_init(const float* __restrict__ x,
                                              const uint4* __restrict__ dhF,
                                              const uint4* __restrict__ dlF,
                                              float2* __restrict__ bm,
                                              u64* __restrict__ l2k) {
    const int c = blockIdx.x, mg = blockIdx.y, b = blockIdx.z;
    const int tid = threadIdx.x;
    const int w = tid >> 6, l = tid & 63;
    const int n = l & 31, h = l >> 5;
    __shared__ float xs[520];
    __shared__ uint4 xw[512];          // packed quads {hi01,hi23,lo01,lo23}
    __shared__ u64 keyL[4 * KW];
    const int t0 = c << 8;
    const float* xp = x + (size_t)b * NS;
    for (int i4 = tid; i4 < 130; i4 += 256) {
        const int i = i4 << 2, g = t0 + i;
        float4 v;
        if (g + 3 < NS) v = *(const float4*)(xp + g);
        else {
            v.x = (g     < NS) ? xp[g]     : 0.f;
            v.y = (g + 1 < NS) ? xp[g + 1] : 0.f;
            v.z = (g + 2 < NS) ? xp[g + 2] : 0.f;
            v.w = (g + 3 < NS) ? xp[g + 3] : 0.f;
        }
        *(float4*)(xs + i) = v;
    }
    __syncthreads();
    for (int i = tid; i < 512; i += 256) {
        const float v0 = xs[i], v1 = xs[i + 1], v2 = xs[i + 2], v3 = xs[i + 3];
        uint4 q;
        q.x = f16hi(v0) | (f16hi(v1) << 16);
        q.y = f16hi(v2) | (f16hi(v3) << 16);
        q.z = f16lo(v0) | (f16lo(v1) << 16);
        q.w = f16lo(v2) | (f16lo(v3) << 16);
        xw[i] = q;
    }
    __syncthreads();

    f32x16 acc00, acc01, acc10, acc11;
#pragma unroll
    for (int j = 0; j < 16; ++j) { acc00[j] = 0.f; acc01[j] = 0.f;
                                   acc10[j] = 0.f; acc11[j] = 0.f; }

    const int abase = (mg << 6) + n;
    const int sbb = (w << 6) + n + (h << 3);

    half8 fbh[4], fbl[4];
    {
        const uint4 q0 = xw[sbb], q1 = xw[sbb + 4];
        const uint4v hv = {q0.x, q0.y, q1.x, q1.y};
        const uint4v lv = {q0.z, q0.w, q1.z, q1.w};
        fbh[0] = __builtin_bit_cast(half8, hv);
        fbl[0] = __builtin_bit_cast(half8, lv);
    }
    {
        const uint4 q0 = xw[sbb + 16], q1 = xw[sbb + 20];
        const uint4v hv = {q0.x, q0.y, q1.x, q1.y};
        const uint4v lv = {q0.z, q0.w, q1.z, q1.w};
        fbh[1] = __builtin_bit_cast(half8, hv);
        fbl[1] = __builtin_bit_cast(half8, lv);
    }

#pragma unroll 4
    for (int kk = 0; kk < 16; ++kk) {
        const int kg = (kk << 1) + h;
        const half8 ah0 = __builtin_bit_cast(half8, dhF[(kg << 8) + abase]);
        const half8 al0 = __builtin_bit_cast(half8, dlF[(kg << 8) + abase]);
        const half8 ah1 = __builtin_bit_cast(half8, dhF[(kg << 8) + abase + 32]);
        const half8 al1 = __builtin_bit_cast(half8, dlF[(kg << 8) + abase + 32]);
        {
            const int sN = sbb + ((kk + 2) << 4);
            const uint4 q0 = xw[sN], q1 = xw[sN + 4];
            const uint4v hv = {q0.x, q0.y, q1.x, q1.y};
            const uint4v lv = {q0.z, q0.w, q1.z, q1.w};
            fbh[(kk + 2) & 3] = __builtin_bit_cast(half8, hv);
            fbl[(kk + 2) & 3] = __builtin_bit_cast(half8, lv);
        }
        const half8 b0h = fbh[kk & 3],       b0l = fbl[kk & 3];
        const half8 b1h = fbh[(kk + 2) & 3], b1l = fbl[(kk + 2) & 3];
        acc00 = __builtin_amdgcn_mfma_f32_32x32x16_f16(ah0, b0l, acc00, 0, 0, 0);
        acc00 = __builtin_amdgcn_mfma_f32_32x32x16_f16(al0, b0h, acc00, 0, 0, 0);
        acc00 = __builtin_amdgcn_mfma_f32_32x32x16_f16(ah0, b0h, acc00, 0, 0, 0);
        acc10 = __builtin_amdgcn_mfma_f32_32x32x16_f16(ah1, b0l, acc10, 0, 0, 0);
        acc10 = __builtin_amdgcn_mfma_f32_32x32x16_f16(al1, b0h, acc10, 0, 0, 0);
        acc10 = __builtin_amdgcn_mfma_f32_32x32x16_f16(ah1, b0h, acc10, 0, 0, 0);
        acc01 = __builtin_amdgcn_mfma_f32_32x32x16_f16(ah0, b1l, acc01, 0, 0, 0);
        acc01 = __builtin_amdgcn_mfma_f32_32x32x16_f16(al0, b1h, acc01, 0, 0, 0);
        acc01 = __builtin_amdgcn_mfma_f32_32x32x16_f16(ah0, b1h, acc01, 0, 0, 0);
        acc11 = __builtin_amdgcn_mfma_f32_32x32x16_f16(ah1, b1l, acc11, 0, 0, 0);
        acc11 = __builtin_amdgcn_mfma_f32_32x32x16_f16(al1, b1h, acc11, 0, 0, 0);
        acc11 = __builtin_amdgcn_mfma_f32_32x32x16_f16(ah1, b1h, acc11, 0, 0, 0);
    }

    // Epilogue: LDS-tail u64 key reduction (r15 form).
    const int tb = t0 + (w << 6) + n;
#pragma unroll
    for (int mt = 0; mt < 2; ++mt) {
#pragma unroll
        for (int r = 0; r < 16; ++r) {
            const int amt = (r & 3) + ((r >> 2) << 3) + (h << 2);
            const int idx0 = ((mg << 6) + (mt << 5) + amt) * TOUT + tb;
            const float v0 = (mt == 0) ? acc00[r] : acc10[r];
            const float v1 = (mt == 0) ? acc01[r] : acc11[r];
            const unsigned int c0 = (0x7FFFFFu - (unsigned int)idx0);
            u64 k0 = 0ull, k1 = 0ull;
            if (tb < TOUT)
                k0 = ((u64)__float_as_uint(fabsf(v0)) << 32)
                   | ((u64)(c0 << 1))
                   | (u64)(__float_as_uint(v0) >> 31);
            if (tb + 32 < TOUT)
                k1 = ((u64)__float_as_uint(fabsf(v1)) << 32)
                   | ((u64)((c0 - 32u) << 1))
                   | (u64)(__float_as_uint(v1) >> 31);
            keyL[w * KW + amt * 33 + n] = (k1 > k0) ? k1 : k0;
        }
        __syncthreads();
        {
            const int inst = tid >> 2, sub = tid & 3;   // inst = amt*2 + p2
            const int p2 = inst & 1, amt = inst >> 1;
            u64 k = 0ull;
#pragma unroll
            for (int j = 0; j < 16; ++j) {
                const int e = sub * 16 + j;
                const u64 ke = keyL[((p2 << 1) + (e >> 5)) * KW + amt * 33 + (e & 31)];
                if (ke > k) k = ke;
            }
#pragma unroll
            for (int m = 1; m <= 2; m <<= 1) {
                const u64 ok = __shfl_xor(k, m, 4);
                if (ok > k) k = ok;
            }
            const int blk = (c << 1) + p2;
            const int atom = (mg << 6) + (mt << 5) + amt;
            if (sub == 0 && blk < NBLK) {
                float bsg; int idx;
                unpackkey(k, bsg, idx);
                bm[(size_t)((b << 8) + atom) * NBLK + blk] =
                    make_float2(bsg, (float)idx);
            }
            const u64 op = __shfl_xor(k, 4, 8);          // partner p2's max
            if ((tid & 7) == 0) {
                const u64 km = (op > k) ? op : k;
                if (km) atomicMax(&l2k[(b << 8) + atom], km);
            }
        }
        __syncthreads();
    }
}

// One MP step (r15 version verbatim, bit-proven).
__global__ __launch_bounds__(512) void k_step(const float* __restrict__ d,
                                              const float* __restrict__ resid_src,
                                              float* __restrict__ resid_dst,
                                              float2* __restrict__ bm,
                                              u64* __restrict__ l2,
                                              int* __restrict__ pos_a,
                                              int* __restrict__ atom_a,
                                              float* __restrict__ amp_a,
                                              int step) {
    const int og = blockIdx.x, b = blockIdx.y;
    const int tid = threadIdx.x;
    const int wave = tid >> 6, lane = tid & 63;
    __shared__ float dt[2048];
    __shared__ float rsu[1024];
    __shared__ u64 sred[8];
    __shared__ float4 upd[8][5];
    __shared__ int sh_pos, sh_atom, sh_prev;
    __shared__ float sh_amp;

    ((float4*)dt)[tid] = ((const float4*)(d + og * 2048))[tid];
    if (tid == 0 && step >= 2) sh_prev = pos_a[(step - 1) * BATCH + b];
    u64* l2r = l2 + (step & 1) * (BATCH * NATOM);
    u64* l2w = l2 + ((step + 1) & 1) * (BATCH * NATOM);

    {
        u64 k = 0ull;
        if (tid < 256) k = l2r[(b << 8) + tid];
#pragma unroll
        for (int m = 1; m <= 32; m <<= 1) {
            const u64 ok = __shfl_xor(k, m);
            if (ok > k) k = ok;
        }
        if (lane == 0) sred[wave] = k;
    }
    __syncthreads();
    if (tid == 0) {
        u64 k = sred[0];
#pragma unroll
        for (int i = 1; i < 8; ++i) if (sred[i] > k) k = sred[i];
        float sig; int idx;
        unpackkey(k, sig, idx);
        const int atom = idx / TOUT;
        const int pos = idx - atom * TOUT;
        sh_pos = pos; sh_atom = atom; sh_amp = sig;
        if (og == 0) {
            pos_a[step * BATCH + b] = pos;
            atom_a[step * BATCH + b] = atom;
            amp_a[step * BATCH + b] = sig;
        }
    }
    __syncthreads();
    const int p = sh_pos, atom_s = sh_atom;
    const float amp = sh_amp;

    if (step < 2) {
        for (int i = tid; i < 1024; i += 512) {
            const int g = (og << 10) + i;
            float v = resid_src[(size_t)b * NS + g];
            const int off = g - p;
            if (off >= 0 && off < KER)
                v = __fsub_rn(v, __fmul_rn(amp, d[atom_s * KER + off]));
            resid_dst[(size_t)b * NS + g] = v;
        }
    } else if (og == 0) {
        if (tid < 256) {
            const int g = p + tid;
            resid_dst[(size_t)b * NS + g] =
                __fsub_rn(resid_src[(size_t)b * NS + g],
                          __fmul_rn(amp, d[atom_s * KER + tid]));
        } else {
            const int g = sh_prev + (tid - 256);
            if (g < p || g > p + 255)
                resid_dst[(size_t)b * NS + g] = resid_src[(size_t)b * NS + g];
        }
    }

    int tlo = p - 255; if (tlo < 0) tlo = 0;
    int thi = p + 255; if (thi > TOUT - 1) thi = TOUT - 1;
    const int bs0 = tlo >> 7, be0 = thi >> 7;
    const int rbase = bs0 << 7;
    const int nblks = be0 - bs0 + 1;
    const int rlen = (nblks << 7) + 255;
    for (int i = tid; i < rlen; i += 512) {
        const int g = rbase + i;
        float v = (g < NS) ? resid_src[(size_t)b * NS + g] : 0.f;
        const int off = g - p;
        if (g < NS && off >= 0 && off < KER)
            v = __fsub_rn(v, __fmul_rn(amp, d[atom_s * KER + off]));
        rsu[SW4(i)] = v;
    }
    __syncthreads();

    const int lg = lane >> 4, l16 = lane & 15;
    const float* dp = dt + (wave << 8) + (lg << 6);
    const int atomg = (og << 3) + wave;
    for (int bb = 0; bb < nblks; ++bb) {
        const int blk = bs0 + bb;
        const int t0r = (bb << 7) + (l16 << 3) + (lg << 6);
        float acc[8];
#pragma unroll
        for (int j = 0; j < 8; ++j) acc[j] = 0.f;
        float4 A0 = *(const float4*)(rsu + SW4(t0r));
        float4 A1 = *(const float4*)(rsu + SW4(t0r + 4));
        float4 B0 = *(const float4*)(rsu + SW4(t0r + 8));
        float4 B1 = *(const float4*)(rsu + SW4(t0r + 12));
#pragma unroll
        for (int kk = 0; kk < 64; kk += 16) {
            const float4 d0 = *(const float4*)(dp + kk);
            const float4 d1 = *(const float4*)(dp + kk + 4);
            const float4 N0 = *(const float4*)(rsu + SW4(t0r + kk + 16));
            const float4 N1 = *(const float4*)(rsu + SW4(t0r + kk + 20));
            fma8(acc, d0, d1, A0, A1, B0, B1);
            const float4 d2 = *(const float4*)(dp + kk + 8);
            const float4 d3 = *(const float4*)(dp + kk + 12);
            const float4 M0 = *(const float4*)(rsu + SW4(t0r + kk + 24));
            const float4 M1 = *(const float4*)(rsu + SW4(t0r + kk + 28));
            fma8(acc, d2, d3, B0, B1, N0, N1);
            A0 = N0; A1 = N1; B0 = M0; B1 = M1;
        }
#pragma unroll
        for (int j = 0; j < 8; ++j) {
            acc[j] += __shfl_xor(acc[j], 16);
            acc[j] += __shfl_xor(acc[j], 32);
        }
        float ba = -1.f, bsg = 0.f, bi = 3.0e7f;
        const int tbp = rbase + (bb << 7) + (l16 << 3);
#pragma unroll
        for (int j = 0; j < 8; ++j) {
            const int t = tbp + j;
            const float av = fabsf(acc[j]);
            if (t < TOUT && av > ba) { ba = av; bsg = acc[j]; bi = (float)(atomg * TOUT + t); }
        }
#pragma unroll
        for (int m = 32; m >= 1; m >>= 1) {
            const float oa = __shfl_xor(ba, m);
            const float os = __shfl_xor(bsg, m);
            const float oi = __shfl_xor(bi, m);
            cmax(ba, bsg, bi, oa, os, oi);
        }
        if (lane == 0) {
            bm[(size_t)(b * NATOM + atomg) * NBLK + blk] = make_float2(bsg, bi);
            upd[wave][bb] = make_float4(ba, bsg, bi, 0.f);
        }
    }
    __syncthreads();

    {
        const u64 ko = l2r[(b << 8) + atomg];
        float eox; int eidx;
        unpackkey(ko, eox, eidx);
        const int oblk = (eidx - atomg * TOUT) >> 7;
        if (oblk >= bs0 && oblk <= be0) {
            float ba = -1.f, bsg = 0.f, bi = 3.0e7f;
            const float2* row = bm + (size_t)(b * NATOM + atomg) * NBLK;
            for (int i = lane; i < NBLK; i += 64) {
                if (i >= bs0 && i <= be0) {
                    const float4 e2 = upd[wave][i - bs0];
                    cmax(ba, bsg, bi, e2.x, e2.y, e2.z);
                } else {
                    const float2 e2 = row[i];
                    cmax(ba, bsg, bi, fabsf(e2.x), e2.x, e2.y);
                }
            }
#pragma unroll
            for (int m = 32; m >= 1; m >>= 1) {
                const float oa = __shfl_xor(ba, m);
                const float os = __shfl_xor(bsg, m);
                const float oi = __shfl_xor(bi, m);
                cmax(ba, bsg, bi, oa, os, oi);
            }
            if (lane == 0) l2w[(b << 8) + atomg] = packkey(bsg, (int)bi);
        } else if (lane == 0) {
            u64 k = ko;
            for (int bb = 0; bb < nblks; ++bb) {
                const float4 e2 = upd[wave][bb];
                const u64 ku = packkey(e2.y, (int)e2.z);
                if (ku > k) k = ku;
            }
            l2w[(b << 8) + atomg] = k;
        }
    }
}

// Head; blocks with s==15 compute the final select inline from l2 parity buf.
__global__ __launch_bounds__(128) void k_head(const int* __restrict__ pos_a,
                                              const int* __restrict__ atom_a,
                                              const float* __restrict__ amp_a,
                                              const u64* __restrict__ l2,
                                              const float* __restrict__ wpa,
                                              const float* __restrict__ bpa,
                                              const float* __restrict__ wat,
                                              const float* __restrict__ bat,
                                              const float* __restrict__ wr,
                                              const float* __restrict__ br,
                                              float* __restrict__ out) {
    const int s = blockIdx.x, b = blockIdx.y;
    const int o = threadIdx.x;
    __shared__ u64 hred[2];
    __shared__ int sh_pos, sh_atom;
    __shared__ float sh_amp;
    int pos, atom; float amp;
    if (s == NSTEP - 1) {
        const u64* l2r = l2 + ((NSTEP - 1) & 1) * (BATCH * NATOM);
        u64 k = l2r[(b << 8) + o];
        const u64 k2 = l2r[(b << 8) + 128 + o];
        if (k2 > k) k = k2;
#pragma unroll
        for (int m = 1; m <= 32; m <<= 1) {
            const u64 ok = __shfl_xor(k, m);
            if (ok > k) k = ok;
        }
        if ((o & 63) == 0) hred[o >> 6] = k;
        __syncthreads();
        if (o == 0) {
            u64 r = hred[0];
            if (hred[1] > r) r = hred[1];
            float sig; int idx;
            unpackkey(r, sig, idx);
            sh_atom = idx / TOUT;
            sh_pos = idx - sh_atom * TOUT;
            sh_amp = sig;
        }
        __syncthreads();
        pos = sh_pos; atom = sh_atom; amp = sh_amp;
    } else {
        pos  = pos_a[s * BATCH + b];
        atom = atom_a[s * BATCH + b];
        amp  = amp_a[s * BATCH + b];
    }
    const float posn = (float)pos / 32513.0f;
    float sum = br[o];
    for (int c = 0; c < 128; ++c) {
        const float pa = wpa[c * 2] * posn + wpa[c * 2 + 1] * amp + bpa[c];
        const float at = wat[c * 256 + atom] + bat[c];
        sum += wr[o * 256 + c] * pa + wr[o * 256 + 128 + c] * at;
    }
    out[(b * 128 + o) * NSTEP + s] = sum;
}

extern "C" void kernel_launch(void* const* d_in, const int* in_sizes, int n_in,
                              void* d_out, int out_size, void* d_ws, size_t ws_size,
                              hipStream_t stream) {
    const float* x   = (const float*)d_in[0];
    const float* d   = (const float*)d_in[1];
    const float* wpa = (const float*)d_in[2];
    const float* bpa = (const float*)d_in[3];
    const float* wat = (const float*)d_in[4];
    const float* bat = (const float*)d_in[5];
    const float* wr  = (const float*)d_in[6];
    const float* br  = (const float*)d_in[7];
    float* out = (float*)d_out;

    char* ws = (char*)d_ws;
    float2* bm    = (float2*)ws;                                    // 4,177,920
    u64*    l2k   = (u64*)(ws + 4177920);                           // 32,768
    int*    pos_a  = (int*)(ws + 4210688);                          // 512
    int*    atom_a = (int*)(ws + 4211200);                          // 512
    float*  amp_a  = (float*)(ws + 4211712);                        // 512
    uint4*  dhF    = (uint4*)(ws + 4212224);                        // 131,072
    uint4*  dlF    = (uint4*)(ws + 4343296);                        // 131,072
    float*  resid0 = (float*)(ws + 4474368);                        // 1,048,576
    float*  resid1 = (float*)(ws + 5522944);                        // 1,048,576

    const int prep_n = NATOM * 32 + 2 * BATCH * NATOM;              // 12288
    k_prep<<<(prep_n + 255) / 256, 256, 0, stream>>>(d, dhF, dlF, l2k);
    k_init<<<dim3(128, 4, 8), 256, 0, stream>>>(x, dhF, dlF, bm, l2k);
    // Step 0 reads x directly (r_0 = x); steps 0/1 fully populate dst buffers,
    // steps >=2 write only the two changed 256-sample windows.
    for (int st = 0; st < NSTEP - 1; ++st) {
        const float* rs = (st == 0) ? x : ((st & 1) ? resid1 : resid0);
        float* rd = (st & 1) ? resid0 : resid1;
        k_step<<<dim3(32, 8), 512, 0, stream>>>(d, rs, rd, bm, l2k,
                                                pos_a, atom_a, amp_a, st);
    }
    k_head<<<dim3(16, 8), 128, 0, stream>>>(pos_a, atom_a, amp_a, l2k,
                                            wpa, bpa, wat, bat, wr, br, out);
}